// Round 3
// baseline (519.670 us; speedup 1.0000x reference)
//
#include <hip/hip_runtime.h>
#include <hip/hip_bf16.h>
#include <stdint.h>

#define SEQLEN 512
#define NBATCH 64
#define KDIM   512
#define HDIM   1024
#define MTOT   (SEQLEN * NBATCH)   // 32768
#define NTOT   (3 * HDIM)          // 3072
#define STRIDE (NBATCH * HDIM)     // 65536

typedef __attribute__((ext_vector_type(4))) float f32x4;
typedef _Float16 f16x8 __attribute__((ext_vector_type(8)));

// ---------- conversion: fp32 -> (hi, lo) fp16 split planes ---------------
// v = hi + lo exactly to ~2^-24 relative; 3-pass MFMA on splits ~= fp32 GEMM.
__global__ __launch_bounds__(256) void cvt_x(const float* __restrict__ x,
                                             _Float16* __restrict__ xh,
                                             _Float16* __restrict__ xl) {
    int i = blockIdx.x * 256 + threadIdx.x;   // M*K/8 threads, 8 elems each
    const float4* s = (const float4*)(x + (size_t)i * 8);
    float4 a = s[0], b = s[1];
    float v[8] = {a.x, a.y, a.z, a.w, b.x, b.y, b.z, b.w};
    f16x8 hi, lo;
#pragma unroll
    for (int j = 0; j < 8; ++j) {
        _Float16 h = (_Float16)v[j];
        hi[j] = h;
        lo[j] = (_Float16)(v[j] - (float)h);
    }
    *(f16x8*)(xh + (size_t)i * 8) = hi;
    *(f16x8*)(xl + (size_t)i * 8) = lo;
}

__global__ __launch_bounds__(256) void cvt_u(const float* __restrict__ Uc,
                                             const float* __restrict__ Ua,
                                             const float* __restrict__ Uh,
                                             _Float16* __restrict__ uh,
                                             _Float16* __restrict__ ul) {
    int i = blockIdx.x * 256 + threadIdx.x;   // NTOT*K/8 threads
    int n = i >> 6;
    int kb = (i & 63) * 8;
    const float* src = (n < HDIM) ? (Uc + (size_t)n * KDIM)
                     : (n < 2 * HDIM) ? (Ua + (size_t)(n - HDIM) * KDIM)
                     : (Uh + (size_t)(n - 2 * HDIM) * KDIM);
    const float4* s = (const float4*)(src + kb);
    float4 a = s[0], b = s[1];
    float v[8] = {a.x, a.y, a.z, a.w, b.x, b.y, b.z, b.w};
    f16x8 hi, lo;
#pragma unroll
    for (int j = 0; j < 8; ++j) {
        _Float16 h = (_Float16)v[j];
        hi[j] = h;
        lo[j] = (_Float16)(v[j] - (float)h);
    }
    *(f16x8*)(uh + (size_t)n * KDIM + kb) = hi;
    *(f16x8*)(ul + (size_t)n * KDIM + kb) = lo;
}

// --------- GEMM: proj[M][3072] = (Xh+Xl) · (Uh+Ul)^T, 3-pass split -------
// m97 structure: 128x128 tile, BK=32, 4 waves (2x2), 4x4 16x16x32 frags,
// global_load_lds width 16, single-buffered 2-barrier K-loop.
// LDS chunk swizzle: stored_chunk = c ^ ((row>>1)&3)  (16B chunks, 4/row)
//   -> ds_read_b128 bank_start = 16*(row&1) + 4*(c^q(row)): 2 lanes/bank = free.
//   Applied on BOTH sides: global-source chunk permute (store) + read addr.
#define BM 128
#define BN 128
#define BK 32
#define NT_N (NTOT / BN)   // 24
#define GRID ((MTOT / BM) * NT_N)   // 6144, %8 == 0 -> simple bijective T1

__device__ __forceinline__ void gload16(const _Float16* g, _Float16* l) {
    __builtin_amdgcn_global_load_lds((const __attribute__((address_space(1))) void*)g,
                                     (__attribute__((address_space(3))) void*)l,
                                     16, 0, 0);
}

__global__ __launch_bounds__(256) void gemm_f16x2(const _Float16* __restrict__ Ah,
                                                  const _Float16* __restrict__ Al,
                                                  const _Float16* __restrict__ Bh,
                                                  const _Float16* __restrict__ Bl,
                                                  float* __restrict__ pc,
                                                  float* __restrict__ pa,
                                                  float* __restrict__ ph) {
    __shared__ _Float16 lds[4 * BM * BK];   // 32 KB: Ah | Al | Bh | Bl tiles
    _Float16* sAh = lds;
    _Float16* sAl = lds + BM * BK;
    _Float16* sBh = lds + 2 * BM * BK;
    _Float16* sBl = lds + 3 * BM * BK;

    // T1 XCD-aware swizzle: 8 XCDs, 6144 blocks -> 768-block contiguous chunks
    int bid  = (blockIdx.x & 7) * (GRID / 8) + (blockIdx.x >> 3);
    int bm   = bid / NT_N;          // A-panel-major within each XCD chunk
    int bn   = bid % NT_N;
    int tid  = threadIdx.x;
    int lane = tid & 63;
    int wave = tid >> 6;
    int wr   = wave >> 1;           // 2x2 wave grid, 64x64 each
    int wc   = wave & 1;

    // staging: thread t -> row r=t>>2 (LDS slot chunk sc=t&3); the slot holds
    // global chunk sc ^ ((r>>1)&3) = (t&3) ^ ((t>>3)&3).  (row+64: same xor)
    size_t row_off = (size_t)(tid >> 2) * KDIM
                   + (size_t)((((tid & 3) ^ ((tid >> 3) & 3))) * 8);
    const _Float16* gah0 = Ah + (size_t)bm * BM * KDIM + row_off;
    const _Float16* gal0 = Al + (size_t)bm * BM * KDIM + row_off;
    const _Float16* gbh0 = Bh + (size_t)bn * BN * KDIM + row_off;
    const _Float16* gbl0 = Bl + (size_t)bn * BN * KDIM + row_off;
    const size_t half_panel = (size_t)64 * KDIM;
    _Float16* lah = sAh + tid * 8;
    _Float16* lal = sAl + tid * 8;
    _Float16* lbh = sBh + tid * 8;
    _Float16* lbl = sBl + tid * 8;

    f32x4 acc[4][4];
#pragma unroll
    for (int mi = 0; mi < 4; ++mi)
#pragma unroll
        for (int ni = 0; ni < 4; ++ni)
            acc[mi][ni] = (f32x4){0.f, 0.f, 0.f, 0.f};

    int ro = lane & 15;           // row within 16x16 frag
    // swizzled k-chunk: want global chunk cc=lane>>4 of row ro ->
    // stored at chunk cc ^ ((ro>>1)&3); ((ro>>1)&3) == ((lane>>1)&3)
    int ko = (((lane >> 4) ^ ((lane >> 1) & 3)) * 8);

    for (int kt = 0; kt < KDIM / BK; ++kt) {
        int g = kt * BK;
        gload16(gah0 + g, lah);
        gload16(gah0 + half_panel + g, lah + 2048);
        gload16(gal0 + g, lal);
        gload16(gal0 + half_panel + g, lal + 2048);
        gload16(gbh0 + g, lbh);
        gload16(gbh0 + half_panel + g, lbh + 2048);
        gload16(gbl0 + g, lbl);
        gload16(gbl0 + half_panel + g, lbl + 2048);
        __syncthreads();          // compiler drains vmcnt before barrier

        f16x8 ah[4], al[4], bh[4], bl[4];
#pragma unroll
        for (int mi = 0; mi < 4; ++mi) {
            int r = (wr * 64 + mi * 16 + ro) * BK + ko;
            ah[mi] = *(const f16x8*)(sAh + r);
            al[mi] = *(const f16x8*)(sAl + r);
        }
#pragma unroll
        for (int ni = 0; ni < 4; ++ni) {
            int r = (wc * 64 + ni * 16 + ro) * BK + ko;
            bh[ni] = *(const f16x8*)(sBh + r);
            bl[ni] = *(const f16x8*)(sBl + r);
        }
#pragma unroll
        for (int mi = 0; mi < 4; ++mi)
#pragma unroll
            for (int ni = 0; ni < 4; ++ni) {
                acc[mi][ni] = __builtin_amdgcn_mfma_f32_16x16x32_f16(
                    ah[mi], bl[ni], acc[mi][ni], 0, 0, 0);
                acc[mi][ni] = __builtin_amdgcn_mfma_f32_16x16x32_f16(
                    al[mi], bh[ni], acc[mi][ni], 0, 0, 0);
                acc[mi][ni] = __builtin_amdgcn_mfma_f32_16x16x32_f16(
                    ah[mi], bh[ni], acc[mi][ni], 0, 0, 0);
            }
        __syncthreads();
    }

    // epilogue: D col=lane&15 (N), row=(lane>>4)*4+r (M)  [m89-verified]
    int n0 = bn * BN;
    float* outp; int nb;
    if (n0 < HDIM)            { outp = pc; nb = n0; }
    else if (n0 < 2 * HDIM)   { outp = pa; nb = n0 - HDIM; }
    else                      { outp = ph; nb = n0 - 2 * HDIM; }

#pragma unroll
    for (int mi = 0; mi < 4; ++mi)
#pragma unroll
        for (int ni = 0; ni < 4; ++ni) {
            int m = bm * BM + wr * 64 + mi * 16 + (lane >> 4) * 4;
            int n = nb + wc * 64 + ni * 16 + (lane & 15);
#pragma unroll
            for (int r = 0; r < 4; ++r)
                outp[(size_t)(m + r) * HDIM + n] = acc[mi][ni][r];
        }
}

// ------------------------- recurrence ------------------------------------
// one thread per (b,j); 65536 threads; depth-8 register prefetch pipeline.
// ph lives in d_out (GEMM output), overwritten in-place with y (same thread
// owns both addresses; prefetch of out[s+8] precedes write of out[s+8]).
__global__ __launch_bounds__(256) void recur(const float* __restrict__ pc_a,
                                             const float* __restrict__ pa_a,
                                             float* out,
                                             const float* __restrict__ h0,
                                             const float* __restrict__ wc_,
                                             const float* __restrict__ bc_,
                                             const float* __restrict__ wa_,
                                             const float* __restrict__ ba_,
                                             const float* __restrict__ bh_) {
    int idx = blockIdx.x * 256 + threadIdx.x;   // 65536
    int j = idx & (HDIM - 1);
    float h  = h0[idx];
    float wc = wc_[j], bc = bc_[j];
    float wa = wa_[j], ba = ba_[j];
    float bh = bh_[j];

#define PF 8
    float pc[PF], pa[PF], ph[PF];
#pragma unroll
    for (int u = 0; u < PF; ++u) {
        pc[u] = pc_a[(size_t)u * STRIDE + idx];
        pa[u] = pa_a[(size_t)u * STRIDE + idx];
        ph[u] = out [(size_t)u * STRIDE + idx];
    }

    for (int sb = 0; sb < SEQLEN; sb += PF) {
#pragma unroll
        for (int u = 0; u < PF; ++u) {
            int s = sb + u;
            float vc = pc[u], va = pa[u], vh = ph[u];
            int sp = s + PF; sp = (sp < SEQLEN) ? sp : (SEQLEN - 1);  // clamped dead-prefetch
            pc[u] = pc_a[(size_t)sp * STRIDE + idx];
            pa[u] = pa_a[(size_t)sp * STRIDE + idx];
            ph[u] = out [(size_t)sp * STRIDE + idx];

            // match reference op order: proj = xU + b (GEMM is raw xU)
            float zc = (vc + bc) + wc * h;
            float za = (va + ba) + wa * h;
            float c  = 1.0f / (1.0f + expf(-zc));
            float a  = 1.0f + tanhf(za);
            float ht = tanhf((vh + bh) + a * h);
            h = c * h + (1.0f - c) * ht;
            out[(size_t)s * STRIDE + idx] = h;
        }
    }
    out[(size_t)SEQLEN * STRIDE + idx] = h;   // hn
}

// --------------------------- launch --------------------------------------
extern "C" void kernel_launch(void* const* d_in, const int* in_sizes, int n_in,
                              void* d_out, int out_size, void* d_ws, size_t ws_size,
                              hipStream_t stream) {
    const float* x_seq = (const float*)d_in[0];
    const float* h0    = (const float*)d_in[1];
    const float* U_c   = (const float*)d_in[2];
    const float* w_c   = (const float*)d_in[3];
    const float* b_c   = (const float*)d_in[4];
    const float* U_a   = (const float*)d_in[5];
    const float* w_a   = (const float*)d_in[6];
    const float* b_a   = (const float*)d_in[7];
    const float* U_h   = (const float*)d_in[8];
    const float* b_h   = (const float*)d_in[9];
    float* out = (float*)d_out;

    char* ws = (char*)d_ws;
    const size_t MB = 1024 * 1024;
    float*    ws_pc = (float*)ws;                        // 128 MB
    float*    ws_pa = (float*)(ws + 128 * MB);           // 128 MB
    _Float16* x_hi  = (_Float16*)(ws + 256 * MB);        // 32 MB
    _Float16* x_lo  = (_Float16*)(ws + 288 * MB);        // 32 MB
    _Float16* u_hi  = (_Float16*)(ws + 320 * MB);        // 3 MB
    _Float16* u_lo  = (_Float16*)(ws + 323 * MB);        // 3 MB  (total 326 MB)

    cvt_x<<<dim3(MTOT * KDIM / 8 / 256), dim3(256), 0, stream>>>(x_seq, x_hi, x_lo);
    cvt_u<<<dim3(NTOT * KDIM / 8 / 256), dim3(256), 0, stream>>>(U_c, U_a, U_h, u_hi, u_lo);
    gemm_f16x2<<<dim3(GRID), dim3(256), 0, stream>>>(
        x_hi, x_lo, u_hi, u_lo, ws_pc, ws_pa, out);
    recur<<<dim3(STRIDE / 256), dim3(256), 0, stream>>>(ws_pc, ws_pa, out, h0,
                                                        w_c, b_c, w_a, b_a, b_h);
}

// Round 4
// 482.828 us; speedup vs baseline: 1.0763x; 1.0763x over previous
//
#include <hip/hip_runtime.h>
#include <hip/hip_bf16.h>
#include <stdint.h>

#define SEQLEN 512
#define NBATCH 64
#define KDIM   512
#define HDIM   1024
#define MTOT   (SEQLEN * NBATCH)   // 32768
#define NTOT   (3 * HDIM)          // 3072
#define STRIDE (NBATCH * HDIM)     // 65536

typedef __attribute__((ext_vector_type(4))) float f32x4;
typedef _Float16 f16x8 __attribute__((ext_vector_type(8)));

// ---------- conversion: fp32 -> (hi, lo) fp16 split planes ---------------
__global__ __launch_bounds__(256) void cvt_x(const float* __restrict__ x,
                                             _Float16* __restrict__ xh,
                                             _Float16* __restrict__ xl) {
    int i = blockIdx.x * 256 + threadIdx.x;
    const float4* s = (const float4*)(x + (size_t)i * 8);
    float4 a = s[0], b = s[1];
    float v[8] = {a.x, a.y, a.z, a.w, b.x, b.y, b.z, b.w};
    f16x8 hi, lo;
#pragma unroll
    for (int j = 0; j < 8; ++j) {
        _Float16 h = (_Float16)v[j];
        hi[j] = h;
        lo[j] = (_Float16)(v[j] - (float)h);
    }
    *(f16x8*)(xh + (size_t)i * 8) = hi;
    *(f16x8*)(xl + (size_t)i * 8) = lo;
}

__global__ __launch_bounds__(256) void cvt_u(const float* __restrict__ Uc,
                                             const float* __restrict__ Ua,
                                             const float* __restrict__ Uh,
                                             _Float16* __restrict__ uh,
                                             _Float16* __restrict__ ul) {
    int i = blockIdx.x * 256 + threadIdx.x;
    int n = i >> 6;
    int kb = (i & 63) * 8;
    const float* src = (n < HDIM) ? (Uc + (size_t)n * KDIM)
                     : (n < 2 * HDIM) ? (Ua + (size_t)(n - HDIM) * KDIM)
                     : (Uh + (size_t)(n - 2 * HDIM) * KDIM);
    const float4* s = (const float4*)(src + kb);
    float4 a = s[0], b = s[1];
    float v[8] = {a.x, a.y, a.z, a.w, b.x, b.y, b.z, b.w};
    f16x8 hi, lo;
#pragma unroll
    for (int j = 0; j < 8; ++j) {
        _Float16 h = (_Float16)v[j];
        hi[j] = h;
        lo[j] = (_Float16)(v[j] - (float)h);
    }
    *(f16x8*)(uh + (size_t)n * KDIM + kb) = hi;
    *(f16x8*)(ul + (size_t)n * KDIM + kb) = lo;
}

// --------- GEMM: proj[M][3072] = (Xh+Xl)·(Uh+Ul)^T, 3-pass split ---------
// 256x256 tile, BK=32, 512 thr = 8 waves (2M x 4N), 4 planes (Ah,Al,Bh,Bl),
// double-buffered 128 KB LDS, 4-phase-per-K-tile schedule with counted
// vmcnt(8) (T3+T4), setprio around MFMA clusters (T5), chunk-XOR LDS
// swizzle (T2, measured conflict-free in round 3).
#define BM 256
#define BN 256
#define BK 32
#define NT_N (NTOT / BN)            // 12
#define GRID ((MTOT / BM) * NT_N)   // 1536
#define KT_N (KDIM / BK)            // 16

__device__ __forceinline__ void gload16(const _Float16* g, _Float16* l) {
    __builtin_amdgcn_global_load_lds((const __attribute__((address_space(1))) void*)g,
                                     (__attribute__((address_space(3))) void*)l,
                                     16, 0, 0);
}

__device__ __forceinline__ f32x4 mfma16(f16x8 a, f16x8 b, f32x4 c) {
    return __builtin_amdgcn_mfma_f32_16x16x32_f16(a, b, c, 0, 0, 0);
}

__global__ __launch_bounds__(512, 2) void gemm_f16x2(const _Float16* __restrict__ Ah,
                                                     const _Float16* __restrict__ Al,
                                                     const _Float16* __restrict__ Bh,
                                                     const _Float16* __restrict__ Bl,
                                                     float* __restrict__ pc,
                                                     float* __restrict__ pa,
                                                     float* __restrict__ ph) {
    // [buf][plane][256 rows * 32 f16], plane: 0=Ah 1=Al 2=Bh 3=Bl. 128 KB.
    __shared__ _Float16 lds[2][4][BM * BK];

    int bid  = blockIdx.x;          // default dispatch; A-panel-major
    int bm   = bid / NT_N;
    int bn   = bid % NT_N;
    int tid  = threadIdx.x;
    int lane = tid & 63;
    int wave = tid >> 6;
    int wr   = wave >> 2;           // 0..1  (M half)
    int wc   = wave & 3;            // 0..3  (N quarter), wave tile 128x64

    // ---- staging addresses (T2 source-side chunk permute) ----
    // slot s (per plane): row=s>>2, stored chunk sc=s&3 holds global chunk
    // sc ^ ((row>>1)&3).  Thread t covers s=t and s=t+512 (same xor).
    size_t row_off = (size_t)(tid >> 2) * KDIM
                   + (size_t)(((tid & 3) ^ ((tid >> 3) & 3)) * 8);
    const _Float16* gAh = Ah + (size_t)bm * BM * KDIM + row_off;
    const _Float16* gAl = Al + (size_t)bm * BM * KDIM + row_off;
    const _Float16* gBh = Bh + (size_t)bn * BN * KDIM + row_off;
    const _Float16* gBl = Bl + (size_t)bn * BN * KDIM + row_off;
    const size_t HPAN = (size_t)128 * KDIM;   // +128 rows in global
    int t8 = tid * 8;

#define STAGE(b, kt) do { int _g = (kt) * BK;                                  \
    gload16(gAh + _g,        &lds[b][0][t8]);                                  \
    gload16(gAh + HPAN + _g, &lds[b][0][t8 + 4096]);                           \
    gload16(gAl + _g,        &lds[b][1][t8]);                                  \
    gload16(gAl + HPAN + _g, &lds[b][1][t8 + 4096]);                           \
    gload16(gBh + _g,        &lds[b][2][t8]);                                  \
    gload16(gBh + HPAN + _g, &lds[b][2][t8 + 4096]);                           \
    gload16(gBl + _g,        &lds[b][3][t8]);                                  \
    gload16(gBl + HPAN + _g, &lds[b][3][t8 + 4096]); } while (0)

    f32x4 acc[8][4];
#pragma unroll
    for (int i = 0; i < 8; ++i)
#pragma unroll
        for (int j = 0; j < 4; ++j)
            acc[i][j] = (f32x4){0.f, 0.f, 0.f, 0.f};

    int ro = lane & 15;
    // read-side swizzle: global chunk cc=lane>>4 of row `ro+16k` is stored at
    // chunk cc ^ ((ro>>1)&3); ((ro>>1)&3) == ((lane>>1)&3).
    int ko = ((lane >> 4) ^ ((lane >> 1) & 3)) * 8;

    f16x8 a_[4][2], b_[2][2];

#define READ_A(mh) _Pragma("unroll")                                           \
    for (int i = 0; i < 4; ++i) {                                              \
        int row = wr * 128 + ((mh) * 4 + i) * 16 + ro;                         \
        a_[i][0] = *(const f16x8*)(&lds[cur][0][row * BK + ko]);               \
        a_[i][1] = *(const f16x8*)(&lds[cur][1][row * BK + ko]);               \
    }
#define READ_B(nh) _Pragma("unroll")                                           \
    for (int j = 0; j < 2; ++j) {                                              \
        int row = wc * 64 + ((nh) * 2 + j) * 16 + ro;                          \
        b_[j][0] = *(const f16x8*)(&lds[cur][2][row * BK + ko]);               \
        b_[j][1] = *(const f16x8*)(&lds[cur][3][row * BK + ko]);               \
    }
#define MFMA_Q(mh, nh) _Pragma("unroll")                                       \
    for (int i = 0; i < 4; ++i) _Pragma("unroll")                              \
        for (int j = 0; j < 2; ++j) {                                          \
            f32x4 c = acc[(mh) * 4 + i][(nh) * 2 + j];                         \
            c = mfma16(a_[i][0], b_[j][1], c);                                 \
            c = mfma16(a_[i][1], b_[j][0], c);                                 \
            c = mfma16(a_[i][0], b_[j][0], c);                                 \
            acc[(mh) * 4 + i][(nh) * 2 + j] = c;                               \
        }
#define LGKM0 do { asm volatile("s_waitcnt lgkmcnt(0)" ::: "memory");          \
                   __builtin_amdgcn_sched_barrier(0); } while (0)

    STAGE(0, 0);   // prologue: tile 0 -> buf 0

    for (int kt = 0; kt < KT_N; ++kt) {
        int cur = kt & 1;
        if (kt < KT_N - 1) {
            STAGE(1 - cur, kt + 1);                       // prefetch next tile
            asm volatile("s_waitcnt vmcnt(8)" ::: "memory");  // tile kt landed
        } else {
            asm volatile("s_waitcnt vmcnt(0)" ::: "memory");  // tail drain
        }
        __builtin_amdgcn_s_barrier();                     // all waves' kt loads done
        asm volatile("" ::: "memory");

        // P0: quadrant (0,0)
        READ_A(0); READ_B(0);
        LGKM0;
        __builtin_amdgcn_s_setprio(1); MFMA_Q(0, 0); __builtin_amdgcn_s_setprio(0);
        READ_B(1);
        __builtin_amdgcn_s_barrier();
        // P1: quadrant (0,1)
        LGKM0;
        __builtin_amdgcn_s_setprio(1); MFMA_Q(0, 1); __builtin_amdgcn_s_setprio(0);
        READ_A(1);
        __builtin_amdgcn_s_barrier();
        // P2: quadrant (1,1)
        LGKM0;
        __builtin_amdgcn_s_setprio(1); MFMA_Q(1, 1); __builtin_amdgcn_s_setprio(0);
        READ_B(0);
        __builtin_amdgcn_s_barrier();
        // P3: quadrant (1,0)
        LGKM0;
        __builtin_amdgcn_s_setprio(1); MFMA_Q(1, 0); __builtin_amdgcn_s_setprio(0);
        __builtin_amdgcn_s_barrier();   // gates restage of buf[cur] next iter
    }

    // ---- epilogue: C-write. D col=lane&15 (N), row=(lane>>4)*4+r (M) ----
    int n0 = bn * BN;
    float* outp; int nb;
    if (n0 < HDIM)            { outp = pc; nb = n0; }
    else if (n0 < 2 * HDIM)   { outp = pa; nb = n0 - HDIM; }
    else                      { outp = ph; nb = n0 - 2 * HDIM; }

#pragma unroll
    for (int ai = 0; ai < 8; ++ai)
#pragma unroll
        for (int bj = 0; bj < 4; ++bj) {
            int m = bm * BM + wr * 128 + ai * 16 + (lane >> 4) * 4;
            int n = nb + wc * 64 + bj * 16 + (lane & 15);
#pragma unroll
            for (int r = 0; r < 4; ++r)
                outp[(size_t)(m + r) * HDIM + n] = acc[ai][bj][r];
        }
#undef STAGE
#undef READ_A
#undef READ_B
#undef MFMA_Q
#undef LGKM0
}

// ------------------------- recurrence ------------------------------------
// one thread per (b,j); 65536 threads; depth-16 register prefetch pipeline.
__global__ __launch_bounds__(256) void recur(const float* __restrict__ pc_a,
                                             const float* __restrict__ pa_a,
                                             float* out,
                                             const float* __restrict__ h0,
                                             const float* __restrict__ wc_,
                                             const float* __restrict__ bc_,
                                             const float* __restrict__ wa_,
                                             const float* __restrict__ ba_,
                                             const float* __restrict__ bh_) {
    int idx = blockIdx.x * 256 + threadIdx.x;
    int j = idx & (HDIM - 1);
    float h  = h0[idx];
    float wc = wc_[j], bc = bc_[j];
    float wa = wa_[j], ba = ba_[j];
    float bh = bh_[j];

#define PF 16
    float pc[PF], pa[PF], ph[PF];
#pragma unroll
    for (int u = 0; u < PF; ++u) {
        pc[u] = pc_a[(size_t)u * STRIDE + idx];
        pa[u] = pa_a[(size_t)u * STRIDE + idx];
        ph[u] = out [(size_t)u * STRIDE + idx];
    }

    for (int sb = 0; sb < SEQLEN; sb += PF) {
#pragma unroll
        for (int u = 0; u < PF; ++u) {
            int s = sb + u;
            float vc = pc[u], va = pa[u], vh = ph[u];
            int sp = s + PF; sp = (sp < SEQLEN) ? sp : (SEQLEN - 1);
            pc[u] = pc_a[(size_t)sp * STRIDE + idx];
            pa[u] = pa_a[(size_t)sp * STRIDE + idx];
            ph[u] = out [(size_t)sp * STRIDE + idx];

            float zc = (vc + bc) + wc * h;
            float za = (va + ba) + wa * h;
            float c  = 1.0f / (1.0f + expf(-zc));
            float a  = 1.0f + tanhf(za);
            float ht = tanhf((vh + bh) + a * h);
            h = c * h + (1.0f - c) * ht;
            out[(size_t)s * STRIDE + idx] = h;
        }
    }
    out[(size_t)SEQLEN * STRIDE + idx] = h;   // hn
}

// --------------------------- launch --------------------------------------
extern "C" void kernel_launch(void* const* d_in, const int* in_sizes, int n_in,
                              void* d_out, int out_size, void* d_ws, size_t ws_size,
                              hipStream_t stream) {
    const float* x_seq = (const float*)d_in[0];
    const float* h0    = (const float*)d_in[1];
    const float* U_c   = (const float*)d_in[2];
    const float* w_c   = (const float*)d_in[3];
    const float* b_c   = (const float*)d_in[4];
    const float* U_a   = (const float*)d_in[5];
    const float* w_a   = (const float*)d_in[6];
    const float* b_a   = (const float*)d_in[7];
    const float* U_h   = (const float*)d_in[8];
    const float* b_h   = (const float*)d_in[9];
    float* out = (float*)d_out;

    char* ws = (char*)d_ws;
    const size_t MB = 1024 * 1024;
    float*    ws_pc = (float*)ws;                        // 128 MB
    float*    ws_pa = (float*)(ws + 128 * MB);           // 128 MB
    _Float16* x_hi  = (_Float16*)(ws + 256 * MB);        // 32 MB
    _Float16* x_lo  = (_Float16*)(ws + 288 * MB);        // 32 MB
    _Float16* u_hi  = (_Float16*)(ws + 320 * MB);        // 3 MB
    _Float16* u_lo  = (_Float16*)(ws + 323 * MB);        // 3 MB

    cvt_x<<<dim3(MTOT * KDIM / 8 / 256), dim3(256), 0, stream>>>(x_seq, x_hi, x_lo);
    cvt_u<<<dim3(NTOT * KDIM / 8 / 256), dim3(256), 0, stream>>>(U_c, U_a, U_h, u_hi, u_lo);
    gemm_f16x2<<<dim3(GRID), dim3(512), 0, stream>>>(
        x_hi, x_lo, u_hi, u_lo, ws_pc, ws_pa, out);
    recur<<<dim3(STRIDE / 256), dim3(256), 0, stream>>>(ws_pc, ws_pa, out, h0,
                                                        w_c, b_c, w_a, b_a, b_h);
}

// Round 6
// 462.748 us; speedup vs baseline: 1.1230x; 1.0434x over previous
//
#include <hip/hip_runtime.h>
#include <hip/hip_bf16.h>
#include <stdint.h>

#define SEQLEN 512
#define NBATCH 64
#define KDIM   512
#define HDIM   1024
#define MTOT   (SEQLEN * NBATCH)   // 32768
#define NTOT   (3 * HDIM)          // 3072
#define STRIDE (NBATCH * HDIM)     // 65536

typedef __attribute__((ext_vector_type(4))) float f32x4;
typedef _Float16 f16x8 __attribute__((ext_vector_type(8)));

// ---------- conversion: fp32 -> (hi, lo) fp16 split planes ---------------
// v = hi + lo to ~2^-22 relative; 3-pass MFMA (AhBh+AhBl+AlBh) ~= fp32 GEMM.
// (Round-5 measured: 2-pass => absmax 0.51 FAIL; 3-pass => 0.0078 PASS 9x.)
__global__ __launch_bounds__(256) void cvt_x(const float* __restrict__ x,
                                             _Float16* __restrict__ xh,
                                             _Float16* __restrict__ xl) {
    int i = blockIdx.x * 256 + threadIdx.x;
    const float4* s = (const float4*)(x + (size_t)i * 8);
    float4 a = s[0], b = s[1];
    float v[8] = {a.x, a.y, a.z, a.w, b.x, b.y, b.z, b.w};
    f16x8 hi, lo;
#pragma unroll
    for (int j = 0; j < 8; ++j) {
        _Float16 h = (_Float16)v[j];
        hi[j] = h;
        lo[j] = (_Float16)(v[j] - (float)h);
    }
    *(f16x8*)(xh + (size_t)i * 8) = hi;
    *(f16x8*)(xl + (size_t)i * 8) = lo;
}

__global__ __launch_bounds__(256) void cvt_u(const float* __restrict__ Uc,
                                             const float* __restrict__ Ua,
                                             const float* __restrict__ Uh,
                                             _Float16* __restrict__ uh,
                                             _Float16* __restrict__ ul) {
    int i = blockIdx.x * 256 + threadIdx.x;
    int n = i >> 6;
    int kb = (i & 63) * 8;
    const float* src = (n < HDIM) ? (Uc + (size_t)n * KDIM)
                     : (n < 2 * HDIM) ? (Ua + (size_t)(n - HDIM) * KDIM)
                     : (Uh + (size_t)(n - 2 * HDIM) * KDIM);
    const float4* s = (const float4*)(src + kb);
    float4 a = s[0], b = s[1];
    float v[8] = {a.x, a.y, a.z, a.w, b.x, b.y, b.z, b.w};
    f16x8 hi, lo;
#pragma unroll
    for (int j = 0; j < 8; ++j) {
        _Float16 h = (_Float16)v[j];
        hi[j] = h;
        lo[j] = (_Float16)(v[j] - (float)h);
    }
    *(f16x8*)(uh + (size_t)n * KDIM + kb) = hi;
    *(f16x8*)(ul + (size_t)n * KDIM + kb) = lo;
}

// --------- GEMM: proj[M][3072] = (Xh+Xl)·(Uh+Ul)^T, 3-pass split ---------
// 256x256 tile, BK=32, 512 thr = 8 waves (2M x 4N), 4 planes (Ah,Al,Bh,Bl),
// double-buffered 128 KB LDS. Schedule: ONE raw s_barrier per K-tile, no
// intra-body barriers, no lgkmcnt(0) drains — compiler schedules the
// 96-MFMA body, waves drift => LDS pipe overlaps MFMA pipe (round-4 audit:
// lockstep phases serialized 3.7k MFMA + 3.2k LDS cyc/tile).
// All stages post-barrier => double-buffer race-free; per-wave vmcnt(0)
// pre-barrier drains exactly the 8 in-flight loads of tile kt.
#define BM 256
#define BN 256
#define BK 32
#define NT_N (NTOT / BN)            // 12
#define GRID ((MTOT / BM) * NT_N)   // 1536
#define KT_N (KDIM / BK)            // 16

__device__ __forceinline__ void gload16(const _Float16* g, _Float16* l) {
    __builtin_amdgcn_global_load_lds((const __attribute__((address_space(1))) void*)g,
                                     (__attribute__((address_space(3))) void*)l,
                                     16, 0, 0);
}

__device__ __forceinline__ f32x4 mfma16(f16x8 a, f16x8 b, f32x4 c) {
    return __builtin_amdgcn_mfma_f32_16x16x32_f16(a, b, c, 0, 0, 0);
}

__global__ __launch_bounds__(512, 2) void gemm_f16x2(const _Float16* __restrict__ Ah,
                                                     const _Float16* __restrict__ Al,
                                                     const _Float16* __restrict__ Bh,
                                                     const _Float16* __restrict__ Bl,
                                                     float* __restrict__ pc,
                                                     float* __restrict__ pa,
                                                     float* __restrict__ ph) {
    // [buf][plane][256 rows * 32 f16]; plane 0=Ah 1=Al 2=Bh 3=Bl. 128 KB.
    __shared__ _Float16 lds[2][4][BM * BK];

    int bid  = blockIdx.x;          // default order, A-panel-major
    int bm   = bid / NT_N;
    int bn   = bid % NT_N;
    int tid  = threadIdx.x;
    int lane = tid & 63;
    int wave = tid >> 6;
    int wr   = wave >> 2;           // 0..1 (M half)
    int wc   = wave & 3;            // 0..3 (N quarter); wave tile 128x64

    // staging (T2 source-side chunk permute; round-3 PMC: conflicts = 0)
    size_t row_off = (size_t)(tid >> 2) * KDIM
                   + (size_t)(((tid & 3) ^ ((tid >> 3) & 3)) * 8);
    const _Float16* gAh = Ah + (size_t)bm * BM * KDIM + row_off;
    const _Float16* gAl = Al + (size_t)bm * BM * KDIM + row_off;
    const _Float16* gBh = Bh + (size_t)bn * BN * KDIM + row_off;
    const _Float16* gBl = Bl + (size_t)bn * BN * KDIM + row_off;
    const size_t HPAN = (size_t)128 * KDIM;   // +128 rows in global
    int t8 = tid * 8;

#define SPAIR(buf, plane, gp, kt) do { int _g = (kt) * BK;                     \
    gload16((gp) + _g,        &lds[buf][plane][t8]);                           \
    gload16((gp) + HPAN + _g, &lds[buf][plane][t8 + 4096]); } while (0)

    f32x4 acc[8][4];
#pragma unroll
    for (int i = 0; i < 8; ++i)
#pragma unroll
        for (int j = 0; j < 4; ++j)
            acc[i][j] = (f32x4){0.f, 0.f, 0.f, 0.f};

    int ro = lane & 15;
    int ko = ((lane >> 4) ^ ((lane >> 1) & 3)) * 8;   // read-side swizzle

    f16x8 a_[4][2], b_[4][2];

#define READ_A(mh) _Pragma("unroll")                                           \
    for (int i = 0; i < 4; ++i) {                                              \
        int row = wr * 128 + ((mh) * 4 + i) * 16 + ro;                         \
        a_[i][0] = *(const f16x8*)(&lds[cur][0][row * BK + ko]);               \
        a_[i][1] = *(const f16x8*)(&lds[cur][1][row * BK + ko]);               \
    }
#define READ_B() _Pragma("unroll")                                             \
    for (int j = 0; j < 4; ++j) {                                              \
        int row = wc * 64 + j * 16 + ro;                                       \
        b_[j][0] = *(const f16x8*)(&lds[cur][2][row * BK + ko]);               \
        b_[j][1] = *(const f16x8*)(&lds[cur][3][row * BK + ko]);               \
    }
#define MFMA_HALF(mh) _Pragma("unroll")                                        \
    for (int i = 0; i < 4; ++i) _Pragma("unroll")                              \
        for (int j = 0; j < 4; ++j) {                                          \
            f32x4 c = acc[(mh) * 4 + i][j];                                    \
            c = mfma16(a_[i][0], b_[j][1], c);   /* Ah·Bl */                   \
            c = mfma16(a_[i][1], b_[j][0], c);   /* Al·Bh */                   \
            c = mfma16(a_[i][0], b_[j][0], c);   /* Ah·Bh */                   \
            acc[(mh) * 4 + i][j] = c;                                          \
        }

    // prologue: tile 0 -> buf 0 (8 loads)
    SPAIR(0, 0, gAh, 0);
    SPAIR(0, 1, gAl, 0);
    SPAIR(0, 2, gBh, 0);
    SPAIR(0, 3, gBl, 0);

    for (int kt = 0; kt < KT_N; ++kt) {
        int cur = kt & 1, nxt = 1 - cur;
        bool pre = (kt < KT_N - 1);
        // pin all prior MFMAs/ds_reads before the wait+barrier (rule #18),
        // then per-wave drain of tile kt's 8 loads, then block-wide barrier.
        __builtin_amdgcn_sched_barrier(0);
        asm volatile("s_waitcnt vmcnt(0)" ::: "memory");
        __builtin_amdgcn_s_barrier();
        __builtin_amdgcn_sched_barrier(0);

        READ_B();
        READ_A(0);
        if (pre) { SPAIR(nxt, 0, gAh, kt + 1); SPAIR(nxt, 1, gAl, kt + 1); }
        __builtin_amdgcn_s_setprio(1);
        MFMA_HALF(0);
        __builtin_amdgcn_s_setprio(0);
        READ_A(1);
        if (pre) { SPAIR(nxt, 2, gBh, kt + 1); SPAIR(nxt, 3, gBl, kt + 1); }
        __builtin_amdgcn_s_setprio(1);
        MFMA_HALF(1);
        __builtin_amdgcn_s_setprio(0);
    }

    // epilogue: D col=lane&15 (N), row=(lane>>4)*4+r (M)  [m89-verified]
    int n0 = bn * BN;
    float* outp; int nb;
    if (n0 < HDIM)            { outp = pc; nb = n0; }
    else if (n0 < 2 * HDIM)   { outp = pa; nb = n0 - HDIM; }
    else                      { outp = ph; nb = n0 - 2 * HDIM; }

#pragma unroll
    for (int ai = 0; ai < 8; ++ai)
#pragma unroll
        for (int bj = 0; bj < 4; ++bj) {
            int m = bm * BM + wr * 128 + ai * 16 + (lane >> 4) * 4;
            int n = nb + wc * 64 + bj * 16 + (lane & 15);
#pragma unroll
            for (int r = 0; r < 4; ++r)
                outp[(size_t)(m + r) * HDIM + n] = acc[ai][bj][r];
        }
#undef SPAIR
#undef READ_A
#undef READ_B
#undef MFMA_HALF
}

// ------------------------- recurrence ------------------------------------
// one thread per (b,j); 65536 threads; depth-32 register prefetch pipeline.
__global__ __launch_bounds__(256) void recur(const float* __restrict__ pc_a,
                                             const float* __restrict__ pa_a,
                                             float* out,
                                             const float* __restrict__ h0,
                                             const float* __restrict__ wc_,
                                             const float* __restrict__ bc_,
                                             const float* __restrict__ wa_,
                                             const float* __restrict__ ba_,
                                             const float* __restrict__ bh_) {
    int idx = blockIdx.x * 256 + threadIdx.x;
    int j = idx & (HDIM - 1);
    float h  = h0[idx];
    float wc = wc_[j], bc = bc_[j];
    float wa = wa_[j], ba = ba_[j];
    float bh = bh_[j];

#define PF 32
    float pc[PF], pa[PF], ph[PF];
#pragma unroll
    for (int u = 0; u < PF; ++u) {
        pc[u] = pc_a[(size_t)u * STRIDE + idx];
        pa[u] = pa_a[(size_t)u * STRIDE + idx];
        ph[u] = out [(size_t)u * STRIDE + idx];
    }

    for (int sb = 0; sb < SEQLEN; sb += PF) {
#pragma unroll
        for (int u = 0; u < PF; ++u) {
            int s = sb + u;
            float vc = pc[u], va = pa[u], vh = ph[u];
            int sp = s + PF; sp = (sp < SEQLEN) ? sp : (SEQLEN - 1);
            pc[u] = pc_a[(size_t)sp * STRIDE + idx];
            pa[u] = pa_a[(size_t)sp * STRIDE + idx];
            ph[u] = out [(size_t)sp * STRIDE + idx];

            float zc = (vc + bc) + wc * h;
            float za = (va + ba) + wa * h;
            float c  = 1.0f / (1.0f + expf(-zc));
            float a  = 1.0f + tanhf(za);
            float ht = tanhf((vh + bh) + a * h);
            h = c * h + (1.0f - c) * ht;
            out[(size_t)s * STRIDE + idx] = h;
        }
    }
    out[(size_t)SEQLEN * STRIDE + idx] = h;   // hn
}

// --------------------------- launch --------------------------------------
extern "C" void kernel_launch(void* const* d_in, const int* in_sizes, int n_in,
                              void* d_out, int out_size, void* d_ws, size_t ws_size,
                              hipStream_t stream) {
    const float* x_seq = (const float*)d_in[0];
    const float* h0    = (const float*)d_in[1];
    const float* U_c   = (const float*)d_in[2];
    const float* w_c   = (const float*)d_in[3];
    const float* b_c   = (const float*)d_in[4];
    const float* U_a   = (const float*)d_in[5];
    const float* w_a   = (const float*)d_in[6];
    const float* b_a   = (const float*)d_in[7];
    const float* U_h   = (const float*)d_in[8];
    const float* b_h   = (const float*)d_in[9];
    float* out = (float*)d_out;

    char* ws = (char*)d_ws;
    const size_t MB = 1024 * 1024;
    float*    ws_pc = (float*)ws;                        // 128 MB
    float*    ws_pa = (float*)(ws + 128 * MB);           // 128 MB
    _Float16* x_hi  = (_Float16*)(ws + 256 * MB);        // 32 MB
    _Float16* x_lo  = (_Float16*)(ws + 288 * MB);        // 32 MB
    _Float16* u_hi  = (_Float16*)(ws + 320 * MB);        // 3 MB
    _Float16* u_lo  = (_Float16*)(ws + 323 * MB);        // 3 MB

    cvt_x<<<dim3(MTOT * KDIM / 8 / 256), dim3(256), 0, stream>>>(x_seq, x_hi, x_lo);
    cvt_u<<<dim3(NTOT * KDIM / 8 / 256), dim3(256), 0, stream>>>(U_c, U_a, U_h, u_hi, u_lo);
    gemm_f16x2<<<dim3(GRID), dim3(512), 0, stream>>>(
        x_hi, x_lo, u_hi, u_lo, ws_pc, ws_pa, out);
    recur<<<dim3(STRIDE / 256), dim3(256), 0, stream>>>(ws_pc, ws_pa, out, h0,
                                                        w_c, b_c, w_a, b_a, b_h);
}

// Round 7
// 453.252 us; speedup vs baseline: 1.1465x; 1.0209x over previous
//
#include <hip/hip_runtime.h>
#include <hip/hip_bf16.h>
#include <stdint.h>

#define SEQLEN 512
#define NBATCH 64
#define KDIM   512
#define HDIM   1024
#define MTOT   (SEQLEN * NBATCH)   // 32768
#define NTOT   (3 * HDIM)          // 3072
#define STRIDE (NBATCH * HDIM)     // 65536

typedef __attribute__((ext_vector_type(4))) float f32x4;
typedef _Float16 f16x8 __attribute__((ext_vector_type(8)));

// ---------- conversion: fp32 -> (hi, lo) fp16 split planes ---------------
// 3-pass MFMA (AhBh+AhBl+AlBh) ~= fp32 GEMM (r5: 2-pass fails at 0.51).
__global__ __launch_bounds__(256) void cvt_x(const float* __restrict__ x,
                                             _Float16* __restrict__ xh,
                                             _Float16* __restrict__ xl) {
    int i = blockIdx.x * 256 + threadIdx.x;
    const float4* s = (const float4*)(x + (size_t)i * 8);
    float4 a = s[0], b = s[1];
    float v[8] = {a.x, a.y, a.z, a.w, b.x, b.y, b.z, b.w};
    f16x8 hi, lo;
#pragma unroll
    for (int j = 0; j < 8; ++j) {
        _Float16 h = (_Float16)v[j];
        hi[j] = h;
        lo[j] = (_Float16)(v[j] - (float)h);
    }
    *(f16x8*)(xh + (size_t)i * 8) = hi;
    *(f16x8*)(xl + (size_t)i * 8) = lo;
}

__global__ __launch_bounds__(256) void cvt_u(const float* __restrict__ Uc,
                                             const float* __restrict__ Ua,
                                             const float* __restrict__ Uh,
                                             _Float16* __restrict__ uh,
                                             _Float16* __restrict__ ul) {
    int i = blockIdx.x * 256 + threadIdx.x;
    int n = i >> 6;
    int kb = (i & 63) * 8;
    const float* src = (n < HDIM) ? (Uc + (size_t)n * KDIM)
                     : (n < 2 * HDIM) ? (Ua + (size_t)(n - HDIM) * KDIM)
                     : (Uh + (size_t)(n - 2 * HDIM) * KDIM);
    const float4* s = (const float4*)(src + kb);
    float4 a = s[0], b = s[1];
    float v[8] = {a.x, a.y, a.z, a.w, b.x, b.y, b.z, b.w};
    f16x8 hi, lo;
#pragma unroll
    for (int j = 0; j < 8; ++j) {
        _Float16 h = (_Float16)v[j];
        hi[j] = h;
        lo[j] = (_Float16)(v[j] - (float)h);
    }
    *(f16x8*)(uh + (size_t)n * KDIM + kb) = hi;
    *(f16x8*)(ul + (size_t)n * KDIM + kb) = lo;
}

// --------- GEMM: proj[M][3072] = (Xh+Xl)·(Uh+Ul)^T, 3-pass split ---------
// 256x256 tile, BK=32, 512 thr = 8 waves (2M x 4N), 4 planes, 128 KB dbuf.
// Round-7 schedule: cross-barrier REGISTER READ-AHEAD. Per K-tile:
//   READ a1(kt) | MFMA h0 | MFMA h1 | vmcnt(0)+barrier |
//   READ b(kt+1)+a0(kt+1) | stage(kt+2)->freed buf.
// Invariant: all reads of buf[cur] are MFMA-consumed (lgkm complete) before
// the barrier; stage into a buffer only post-barrier after its readers done.
#define BM 256
#define BN 256
#define BK 32
#define NT_N (NTOT / BN)            // 12
#define GRID ((MTOT / BM) * NT_N)   // 1536
#define KT_N (KDIM / BK)            // 16

__device__ __forceinline__ void gload16(const _Float16* g, _Float16* l) {
    __builtin_amdgcn_global_load_lds((const __attribute__((address_space(1))) void*)g,
                                     (__attribute__((address_space(3))) void*)l,
                                     16, 0, 0);
}

__device__ __forceinline__ f32x4 mfma16(f16x8 a, f16x8 b, f32x4 c) {
    return __builtin_amdgcn_mfma_f32_16x16x32_f16(a, b, c, 0, 0, 0);
}

__global__ __launch_bounds__(512, 2) void gemm_f16x2(const _Float16* __restrict__ Ah,
                                                     const _Float16* __restrict__ Al,
                                                     const _Float16* __restrict__ Bh,
                                                     const _Float16* __restrict__ Bl,
                                                     float* __restrict__ pc,
                                                     float* __restrict__ pa,
                                                     float* __restrict__ ph) {
    // [buf][plane][256 rows * 32 f16]; plane 0=Ah 1=Al 2=Bh 3=Bl. 128 KB.
    __shared__ _Float16 lds[2][4][BM * BK];

    int bid  = blockIdx.x;          // default order, A-panel-major
    int bm   = bid / NT_N;
    int bn   = bid % NT_N;
    int tid  = threadIdx.x;
    int lane = tid & 63;
    int wave = tid >> 6;
    int wr   = wave >> 2;           // 0..1 (M half)
    int wc   = wave & 3;            // 0..3 (N quarter); wave tile 128x64

    // staging (T2 source-side chunk permute; round-3 PMC: conflicts = 0)
    size_t row_off = (size_t)(tid >> 2) * KDIM
                   + (size_t)(((tid & 3) ^ ((tid >> 3) & 3)) * 8);
    const _Float16* gAh = Ah + (size_t)bm * BM * KDIM + row_off;
    const _Float16* gAl = Al + (size_t)bm * BM * KDIM + row_off;
    const _Float16* gBh = Bh + (size_t)bn * BN * KDIM + row_off;
    const _Float16* gBl = Bl + (size_t)bn * BN * KDIM + row_off;
    const size_t HPAN = (size_t)128 * KDIM;   // +128 rows in global
    int t8 = tid * 8;

#define SPAIR(buf, plane, gp, kt) do { int _g = (kt) * BK;                     \
    gload16((gp) + _g,        &lds[buf][plane][t8]);                           \
    gload16((gp) + HPAN + _g, &lds[buf][plane][t8 + 4096]); } while (0)
#define STAGE4(buf, kt) do {                                                   \
    SPAIR(buf, 0, gAh, kt); SPAIR(buf, 1, gAl, kt);                            \
    SPAIR(buf, 2, gBh, kt); SPAIR(buf, 3, gBl, kt); } while (0)

    f32x4 acc[8][4];
#pragma unroll
    for (int i = 0; i < 8; ++i)
#pragma unroll
        for (int j = 0; j < 4; ++j)
            acc[i][j] = (f32x4){0.f, 0.f, 0.f, 0.f};

    int ro = lane & 15;
    int ko = ((lane >> 4) ^ ((lane >> 1) & 3)) * 8;   // read-side swizzle

    f16x8 a0_[4][2], a1_[4][2], b_[4][2];

#define READ_AH(arr, buf, mh) _Pragma("unroll")                                \
    for (int i = 0; i < 4; ++i) {                                              \
        int row = wr * 128 + ((mh) * 4 + i) * 16 + ro;                         \
        arr[i][0] = *(const f16x8*)(&lds[buf][0][row * BK + ko]);              \
        arr[i][1] = *(const f16x8*)(&lds[buf][1][row * BK + ko]);              \
    }
#define READ_BB(buf) _Pragma("unroll")                                         \
    for (int j = 0; j < 4; ++j) {                                              \
        int row = wc * 64 + j * 16 + ro;                                       \
        b_[j][0] = *(const f16x8*)(&lds[buf][2][row * BK + ko]);               \
        b_[j][1] = *(const f16x8*)(&lds[buf][3][row * BK + ko]);               \
    }
#define MFMA_HALF(arr, mh) _Pragma("unroll")                                   \
    for (int i = 0; i < 4; ++i) _Pragma("unroll")                              \
        for (int j = 0; j < 4; ++j) {                                          \
            f32x4 c = acc[(mh) * 4 + i][j];                                    \
            c = mfma16(arr[i][0], b_[j][1], c);   /* Ah·Bl */                  \
            c = mfma16(arr[i][1], b_[j][0], c);   /* Al·Bh */                  \
            c = mfma16(arr[i][0], b_[j][0], c);   /* Ah·Bh */                  \
            acc[(mh) * 4 + i][j] = c;                                          \
        }
#define BARRIER_PINNED do {                                                    \
    __builtin_amdgcn_sched_barrier(0);                                         \
    asm volatile("s_waitcnt vmcnt(0)" ::: "memory");                           \
    __builtin_amdgcn_s_barrier();                                              \
    __builtin_amdgcn_sched_barrier(0); } while (0)

    // prologue: tile 0 -> buf0; pre-read b(0), a0(0); stage tile 1 -> buf1
    STAGE4(0, 0);
    BARRIER_PINNED;
    READ_BB(0);
    READ_AH(a0_, 0, 0);
    STAGE4(1, 1);

    for (int kt = 0; kt < KT_N; ++kt) {
        int cur = kt & 1, nxt = 1 - cur;
        READ_AH(a1_, cur, 1);                   // h1 frags of current tile
        __builtin_amdgcn_s_setprio(1);
        MFMA_HALF(a0_, 0);                      // inputs pre-read last iter
        __builtin_amdgcn_s_setprio(0);
        __builtin_amdgcn_s_setprio(1);
        MFMA_HALF(a1_, 1);
        __builtin_amdgcn_s_setprio(0);
        if (kt < KT_N - 1) {
            BARRIER_PINNED;                     // stage(kt+1) landed; readers of
                                                // buf[cur] provably done (above)
            READ_BB(nxt);                       // read-ahead tile kt+1
            READ_AH(a0_, nxt, 0);
            if (kt < KT_N - 2) STAGE4(cur, kt + 2);   // into just-freed buffer
        }
    }

    // epilogue: D col=lane&15 (N), row=(lane>>4)*4+r (M)  [m89-verified]
    int n0 = bn * BN;
    float* outp; int nb;
    if (n0 < HDIM)            { outp = pc; nb = n0; }
    else if (n0 < 2 * HDIM)   { outp = pa; nb = n0 - HDIM; }
    else                      { outp = ph; nb = n0 - 2 * HDIM; }

#pragma unroll
    for (int ai = 0; ai < 8; ++ai)
#pragma unroll
        for (int bj = 0; bj < 4; ++bj) {
            int m = bm * BM + wr * 128 + ai * 16 + (lane >> 4) * 4;
            int n = nb + wc * 64 + bj * 16 + (lane & 15);
#pragma unroll
            for (int r = 0; r < 4; ++r)
                outp[(size_t)(m + r) * HDIM + n] = acc[ai][bj][r];
        }
#undef SPAIR
#undef STAGE4
#undef READ_AH
#undef READ_BB
#undef MFMA_HALF
#undef BARRIER_PINNED
}

// ------------------------- recurrence ------------------------------------
// one thread per (b,j); 65536 threads; depth-32 register prefetch pipeline.
__global__ __launch_bounds__(256) void recur(const float* __restrict__ pc_a,
                                             const float* __restrict__ pa_a,
                                             float* out,
                                             const float* __restrict__ h0,
                                             const float* __restrict__ wc_,
                                             const float* __restrict__ bc_,
                                             const float* __restrict__ wa_,
                                             const float* __restrict__ ba_,
                                             const float* __restrict__ bh_) {
    int idx = blockIdx.x * 256 + threadIdx.x;
    int j = idx & (HDIM - 1);
    float h  = h0[idx];
    float wc = wc_[j], bc = bc_[j];
    float wa = wa_[j], ba = ba_[j];
    float bh = bh_[j];

#define PF 32
    float pc[PF], pa[PF], ph[PF];
#pragma unroll
    for (int u = 0; u < PF; ++u) {
        pc[u] = pc_a[(size_t)u * STRIDE + idx];
        pa[u] = pa_a[(size_t)u * STRIDE + idx];
        ph[u] = out [(size_t)u * STRIDE + idx];
    }

    for (int sb = 0; sb < SEQLEN; sb += PF) {
#pragma unroll
        for (int u = 0; u < PF; ++u) {
            int s = sb + u;
            float vc = pc[u], va = pa[u], vh = ph[u];
            int sp = s + PF; sp = (sp < SEQLEN) ? sp : (SEQLEN - 1);
            pc[u] = pc_a[(size_t)sp * STRIDE + idx];
            pa[u] = pa_a[(size_t)sp * STRIDE + idx];
            ph[u] = out [(size_t)sp * STRIDE + idx];

            float zc = (vc + bc) + wc * h;
            float za = (va + ba) + wa * h;
            float c  = 1.0f / (1.0f + expf(-zc));
            float a  = 1.0f + tanhf(za);
            float ht = tanhf((vh + bh) + a * h);
            h = c * h + (1.0f - c) * ht;
            out[(size_t)s * STRIDE + idx] = h;
        }
    }
    out[(size_t)SEQLEN * STRIDE + idx] = h;   // hn
}

// --------------------------- launch --------------------------------------
extern "C" void kernel_launch(void* const* d_in, const int* in_sizes, int n_in,
                              void* d_out, int out_size, void* d_ws, size_t ws_size,
                              hipStream_t stream) {
    const float* x_seq = (const float*)d_in[0];
    const float* h0    = (const float*)d_in[1];
    const float* U_c   = (const float*)d_in[2];
    const float* w_c   = (const float*)d_in[3];
    const float* b_c   = (const float*)d_in[4];
    const float* U_a   = (const float*)d_in[5];
    const float* w_a   = (const float*)d_in[6];
    const float* b_a   = (const float*)d_in[7];
    const float* U_h   = (const float*)d_in[8];
    const float* b_h   = (const float*)d_in[9];
    float* out = (float*)d_out;

    char* ws = (char*)d_ws;
    const size_t MB = 1024 * 1024;
    float*    ws_pc = (float*)ws;                        // 128 MB
    float*    ws_pa = (float*)(ws + 128 * MB);           // 128 MB
    _Float16* x_hi  = (_Float16*)(ws + 256 * MB);        // 32 MB
    _Float16* x_lo  = (_Float16*)(ws + 288 * MB);        // 32 MB
    _Float16* u_hi  = (_Float16*)(ws + 320 * MB);        // 3 MB
    _Float16* u_lo  = (_Float16*)(ws + 323 * MB);        // 3 MB

    cvt_x<<<dim3(MTOT * KDIM / 8 / 256), dim3(256), 0, stream>>>(x_seq, x_hi, x_lo);
    cvt_u<<<dim3(NTOT * KDIM / 8 / 256), dim3(256), 0, stream>>>(U_c, U_a, U_h, u_hi, u_lo);
    gemm_f16x2<<<dim3(GRID), dim3(512), 0, stream>>>(
        x_hi, x_lo, u_hi, u_lo, ws_pc, ws_pa, out);
    recur<<<dim3(STRIDE / 256), dim3(256), 0, stream>>>(ws_pc, ws_pa, out, h0,
                                                        w_c, b_c, w_a, b_a, b_h);
}